// Round 20
// baseline (194.090 us; speedup 1.0000x reference)
//
#include <hip/hip_runtime.h>

#define Bq 8
#define Cq 256
#define Hq 64
#define Wq 64
#define Nq 4096        // H*W
#define HEADSq 8
#define DIMq 32
#define NCq 256        // compressed tokens 16*16
#define TOPKq 64
#define BHq 64
#define SCALEq 0.17677669529663687f   // 32^-0.5

typedef short bf16x8 __attribute__((ext_vector_type(8)));
typedef float f32x4  __attribute__((ext_vector_type(4)));
typedef float f32x16 __attribute__((ext_vector_type(16)));

// round-to-nearest-even bf16 (top 16 bits)
__device__ __forceinline__ uint32_t f2bf_hi(float f) {
  uint32_t u = __float_as_uint(f);
  return (u + 0x7FFFu + ((u >> 16) & 1u)) >> 16;
}

// split 8 floats into bf16 hi (RNE) + bf16 lo (residual, truncated), packed
__device__ __forceinline__ void split8(const float* v, uint4& hv, uint4& lv) {
  uint32_t h[8], l[8];
#pragma unroll
  for (int j = 0; j < 8; ++j) {
    uint32_t hb = f2bf_hi(v[j]);
    float rest = v[j] - __uint_as_float(hb << 16);
    h[j] = hb;
    l[j] = __float_as_uint(rest) >> 16;
  }
  hv = make_uint4(h[0] | (h[1] << 16), h[2] | (h[3] << 16),
                  h[4] | (h[5] << 16), h[6] | (h[7] << 16));
  lv = make_uint4(l[0] | (l[1] << 16), l[2] | (l[3] << 16),
                  l[4] | (l[5] << 16), l[6] | (l[7] << 16));
}

// 64-row fragment image (8KB = hi 4KB | lo 4KB), element (row,k):
//   region=(row>>5)*2+(k>>4), lane=(row&31)+32*((k&15)>>3), byte=region*1024+lane*16+(k&7)*2
// 32-row image (4KB = hi 2KB | lo 2KB): off=(k>>4)*1024+lane*16, lo at +2048.
// kim16: B-frag-linear K image for 16x16x32: unit (tt,l) at bh*32768 + tt*1024
//   + l*16 (hi; lo +16384) holding K[tok=tt*16+(l&15), k-octet l>>4].

// ---------------- P0: all weight images in ONE launch ---------------------
__global__ __launch_bounds__(256) void prep_wall(
    const float* __restrict__ wq, const float* __restrict__ wk,
    const float* __restrict__ wv, const float* __restrict__ wo,
    char* __restrict__ wt, char* __restrict__ wt32) {
  const int xb = blockIdx.x, s = blockIdx.y, mat = blockIdx.z;
  const int t = threadIdx.x;
  if (mat < 4) {
    const float* w = mat == 0 ? wq : mat == 1 ? wk : mat == 2 ? wv : wo;
    const int o = t & 63, g = t >> 6;
    float v[8];
    const float* src = w + (size_t)(xb * 64 + o) * Cq + s * 32 + g * 8;
#pragma unroll
    for (int j = 0; j < 8; ++j) v[j] = src[j];
    uint4 hv, lv;
    split8(v, hv, lv);
    size_t base = ((size_t)((mat * 4 + xb) * 8 + s)) * 8192;
    int off = ((o >> 5) * 2 + (g >> 1)) * 1024 + ((o & 31) + 32 * (g & 1)) * 16;
    *(uint4*)(wt + base + off) = hv;
    *(uint4*)(wt + base + 4096 + off) = lv;
  } else {
    const int m2 = mat - 4;
    const float* w = m2 == 0 ? wq : m2 == 1 ? wk : wv;
    const int o = t & 31, half = (t >> 5) & 1, g = t >> 6;
    const int oblk = xb * 2 + half;
    float v[8];
    const float* src = w + (size_t)(oblk * 32 + o) * Cq + s * 32 + g * 8;
#pragma unroll
    for (int j = 0; j < 8; ++j) v[j] = src[j];
    uint4 hv, lv;
    split8(v, hv, lv);
    size_t base = ((size_t)((m2 * 8 + oblk) * 8 + s)) * 4096;
    int off = (g >> 1) * 1024 + (o + 32 * (g & 1)) * 16;
    *(uint4*)(wt32 + base + off) = hv;
    *(uint4*)(wt32 + base + 2048 + off) = lv;
  }
}

// ---------------- P2: x -> transposed/split B-frag images (32n x 32k) -----
__global__ __launch_bounds__(256) void prep_x(
    const float* __restrict__ x, char* __restrict__ xt) {
  const int n64 = blockIdx.x, s = blockIdx.y, b = blockIdx.z;
  const int t = threadIdx.x;
  __shared__ float xf[32][64];
  const float* xb = x + ((size_t)(b * Cq + s * 32)) * Nq + n64 * 64;
#pragma unroll
  for (int ii = 0; ii < 2; ++ii) {
    int e = t + ii * 256;
    int cl = e >> 4, n4 = (e & 15) * 4;
    *(float4*)&xf[cl][n4] = *(const float4*)&xb[(size_t)cl * Nq + n4];
  }
  __syncthreads();
  int n = t & 63, g = t >> 6;
  float v[8];
#pragma unroll
  for (int j = 0; j < 8; ++j) v[j] = xf[g * 8 + j][n];
  uint4 hv, lv;
  split8(v, hv, lv);
  char* dst = xt + ((size_t)((b * 8 + s) * 128 + n64 * 2 + (n >> 5))) * 4096;
  int off = (g >> 1) * 1024 + ((n & 31) + 32 * (g & 1)) * 16;
  *(uint4*)(dst + off) = hv;
  *(uint4*)(dst + 2048 + off) = lv;
}

// ---------------- K1: fused qkv projection + pool; emits kim16 ------------
__global__ __launch_bounds__(512) void qkv_fused(
    const char* __restrict__ wt32, const char* __restrict__ xt,
    const float* __restrict__ wck, const float* __restrict__ wcv,
    char* __restrict__ qimg, float* __restrict__ ksc, float* __restrict__ vsc,
    char* __restrict__ kim) {
  const int i = blockIdx.x, oblk = blockIdx.y, b = blockIdx.z;
  const int t = threadIdx.x, l = t & 63, wid = t >> 6;   // wid 0..7
  __shared__ __align__(16) char smem[49152];   // 48KB: W window / pool union

  f32x16 acc[3];
#pragma unroll
  for (int m = 0; m < 3; ++m)
#pragma unroll
    for (int r = 0; r < 16; ++r) acc[m][r] = 0.f;

#pragma unroll 1
  for (int w = 0; w < 2; ++w) {
    __syncthreads();   // waves done reading previous window
#pragma unroll
    for (int u = 0; u < 6; ++u) {
      int e = t + u * 512;
      int sL = e / 768, rem = e - sL * 768;
      int m = rem >> 8, r = rem & 255;
      ((uint4*)smem)[e] =
          ((const uint4*)(wt32 + ((size_t)((m * 8 + oblk) * 8 + w * 4 + sL)) * 4096))[r];
    }
    __syncthreads();
#pragma unroll
    for (int sL = 0; sL < 4; ++sL) {
      const int s = w * 4 + sL;
      bf16x8 xh[2], xl[2];
      {
        const char* xb = xt + ((size_t)((b * 8 + s) * 128 + i * 8 + wid)) * 4096;
#pragma unroll
        for (int kh = 0; kh < 2; ++kh) {
          int off = kh * 1024 + l * 16;
          xh[kh] = *(const bf16x8*)(xb + off);
          xl[kh] = *(const bf16x8*)(xb + 2048 + off);
        }
      }
#pragma unroll
      for (int m = 0; m < 3; ++m) {
        const char* wb = smem + (sL * 3 + m) * 4096;
#pragma unroll
        for (int kh = 0; kh < 2; ++kh) {
          int off = kh * 1024 + l * 16;
          bf16x8 ah = *(const bf16x8*)(wb + off);
          bf16x8 al = *(const bf16x8*)(wb + 2048 + off);
          acc[m] = __builtin_amdgcn_mfma_f32_32x32x16_bf16(ah, xh[kh], acc[m], 0, 0, 0);
          acc[m] = __builtin_amdgcn_mfma_f32_32x32x16_bf16(ah, xl[kh], acc[m], 0, 0, 0);
          acc[m] = __builtin_amdgcn_mfma_f32_32x32x16_bf16(al, xh[kh], acc[m], 0, 0, 0);
        }
      }
    }
  }
  __syncthreads();   // waves done with W window 1; smem now pool scratch

  float* pp    = (float*)smem;            // [8][2][32][8] = 16KB
  float* wpool = (float*)(smem + 16384);  // [2][32][16] = 4KB
  for (int u = t; u < 1024; u += 512) {
    int m = u >> 9, c = (u >> 4) & 31, e = u & 15;
    wpool[(m * 32 + c) * 16 + e] = (m ? wcv : wck)[(oblk * 32 + c) * 16 + e];
  }
  // q emit (register-only; independent of wpool)
  const int bh = b * 8 + oblk;
  {
    char* qb = qimg + ((size_t)(bh * 64 + i * 4 + (wid >> 1))) * 8192;
    const int hi = l >> 5;
    const int rg = (wid & 1) * 2;
    float sw[16];
#pragma unroll
    for (int r = 0; r < 16; ++r) sw[r] = __shfl_xor(acc[0][r], 32);
    float e0[8], e1[8];
#pragma unroll
    for (int j = 0; j < 4; ++j) {
      e0[j]     = hi ? sw[4 + j]      : acc[0][j];
      e0[4 + j] = hi ? acc[0][4 + j]  : sw[j];
      e1[j]     = hi ? sw[12 + j]     : acc[0][8 + j];
      e1[4 + j] = hi ? acc[0][12 + j] : sw[8 + j];
    }
    uint4 h0, l0v, h1, l1v;
    split8(e0, h0, l0v);
    split8(e1, h1, l1v);
    *(uint4*)(qb + rg * 1024 + l * 16) = h0;
    *(uint4*)(qb + 4096 + rg * 1024 + l * 16) = l0v;
    *(uint4*)(qb + (rg + 1) * 1024 + l * 16) = h1;
    *(uint4*)(qb + 4096 + (rg + 1) * 1024 + l * 16) = l1v;
  }
  __syncthreads();   // wpool visible
  // k,v: in-register depthwise pool. spatial row = wid>>1; s-sub = l&3.
#pragma unroll
  for (int m = 1; m <= 2; ++m)
#pragma unroll
    for (int r = 0; r < 16; ++r) {
      int c_l = (r & 3) + 8 * (r >> 2) + 4 * (l >> 5);
      float sv = acc[m][r] * wpool[((m - 1) * 32 + c_l) * 16 + (wid >> 1) * 4 + (l & 3)];
      float t0 = sv + __shfl_xor(sv, 1);
      float s4 = t0 + __shfl_xor(t0, 2);
      if ((l & 3) == 0)
        pp[((wid * 2 + (m - 1)) * 32 + c_l) * 8 + ((l & 31) >> 2)] = s4;
    }
  __syncthreads();
  float* kpool = wpool;            // overwrite wpool (done reading)
  float* vpool = wpool + 512;
  {
    int c = t >> 4, j = t & 15;    // 512 threads cover 32c x 16j
#pragma unroll
    for (int m = 0; m < 2; ++m) {
      int h = j >> 3, jl = j & 7;
      float v = pp[(((0 * 2 + h) * 2 + m) * 32 + c) * 8 + jl] +
                pp[(((1 * 2 + h) * 2 + m) * 32 + c) * 8 + jl] +
                pp[(((2 * 2 + h) * 2 + m) * 32 + c) * 8 + jl] +
                pp[(((3 * 2 + h) * 2 + m) * 32 + c) * 8 + jl];
      (m ? vpool : kpool)[c * 16 + j] = v;
      float* dst = m ? vsc : ksc;
      dst[((size_t)b * Cq + oblk * 32 + c) * NCq + i * 16 + j] = v;
    }
  }
  __syncthreads();
  // kim16 emit: tt == i; unit (tt,l) = K[tok=i*16+(l&15), octet l>>4]
  if (t < 64) {
    int j = l & 15, g = l >> 4;
    float v[8];
#pragma unroll
    for (int jj = 0; jj < 8; ++jj) v[jj] = kpool[(g * 8 + jj) * 16 + j];
    uint4 hv, lv;
    split8(v, hv, lv);
    char* kb = kim + (size_t)bh * 32768 + i * 1024 + l * 16;
    *(uint4*)kb = hv;
    *(uint4*)(kb + 16384) = lv;
  }
}

// ---------------- K3a: stage-1 scores, 16x16x32 MFMA ----------------------
__global__ __launch_bounds__(256) void stage1_mfma(
    const char* __restrict__ qim, const char* __restrict__ kim,
    float* __restrict__ part) {
  const int bh = blockIdx.y, chunk = blockIdx.x;
  const int t = threadIdx.x, l = t & 63, wid = t >> 6;
  __shared__ __align__(16) char kimgL[32768];   // hi 16KB | lo 16KB
  __shared__ float sc[4][256];

  {  // linear coalesced 32KB copy of this bh's kim16
    const uint4* src = (const uint4*)(kim + (size_t)bh * 32768);
#pragma unroll
    for (int ii = 0; ii < 8; ++ii)
      ((uint4*)kimgL)[t + ii * 256] = src[t + ii * 256];
  }
  float scoreacc[16];
#pragma unroll
  for (int tt = 0; tt < 16; ++tt) scoreacc[tt] = 0.f;
  // A-frag byte offset in a 64-row image: row = wid*16+(l&15), g = l>>4
  const int aoff = ((wid >> 1) * 2 + (l >> 5)) * 1024 +
                   ((wid & 1) * 16 + (l & 15) + 32 * ((l >> 4) & 1)) * 16;
  __syncthreads();

#pragma unroll 1
  for (int step = 0; step < 4; ++step) {
    const char* qb = qim + ((size_t)(bh * 64 + chunk * 4 + step)) * 8192;
    bf16x8 ah = *(const bf16x8*)(qb + aoff);
    bf16x8 al = *(const bf16x8*)(qb + 4096 + aoff);
    f32x4 acc[16];
#pragma unroll
    for (int tt = 0; tt < 16; ++tt)
#pragma unroll
      for (int r = 0; r < 4; ++r) acc[tt][r] = 0.f;
#pragma unroll
    for (int tt = 0; tt < 16; ++tt) {
      bf16x8 bhf = *(const bf16x8*)(kimgL + tt * 1024 + l * 16);
      bf16x8 blf = *(const bf16x8*)(kimgL + 16384 + tt * 1024 + l * 16);
      acc[tt] = __builtin_amdgcn_mfma_f32_16x16x32_bf16(ah, bhf, acc[tt], 0, 0, 0);
      acc[tt] = __builtin_amdgcn_mfma_f32_16x16x32_bf16(ah, blf, acc[tt], 0, 0, 0);
      acc[tt] = __builtin_amdgcn_mfma_f32_16x16x32_bf16(al, bhf, acc[tt], 0, 0, 0);
    }
    // softmax: row = (l>>4)*4+r (within wave's 16), token = tt*16+(l&15)
    float mx[4], sm[4];
#pragma unroll
    for (int r = 0; r < 4; ++r) {
      float m = acc[0][r];
#pragma unroll
      for (int tt = 1; tt < 16; ++tt) m = fmaxf(m, acc[tt][r]);
      mx[r] = m;
    }
#pragma unroll
    for (int off = 1; off < 16; off <<= 1)
#pragma unroll
      for (int r = 0; r < 4; ++r) mx[r] = fmaxf(mx[r], __shfl_xor(mx[r], off));
#pragma unroll
    for (int r = 0; r < 4; ++r) sm[r] = 0.f;
#pragma unroll
    for (int tt = 0; tt < 16; ++tt)
#pragma unroll
      for (int r = 0; r < 4; ++r) {
        float e = __expf((acc[tt][r] - mx[r]) * SCALEq);
        acc[tt][r] = e;
        sm[r] += e;
      }
#pragma unroll
    for (int off = 1; off < 16; off <<= 1)
#pragma unroll
      for (int r = 0; r < 4; ++r) sm[r] += __shfl_xor(sm[r], off);
#pragma unroll
    for (int r = 0; r < 4; ++r) sm[r] = 1.0f / sm[r];
#pragma unroll
    for (int tt = 0; tt < 16; ++tt) {
      float tp = acc[tt][0] * sm[0] + acc[tt][1] * sm[1] +
                 acc[tt][2] * sm[2] + acc[tt][3] * sm[3];
      tp += __shfl_xor(tp, 16);
      tp += __shfl_xor(tp, 32);
      scoreacc[tt] += tp;
    }
  }
  if (l < 16) {
#pragma unroll
    for (int tt = 0; tt < 16; ++tt) sc[wid][tt * 16 + l] = scoreacc[tt];
  }
  __syncthreads();
  {
    float v = sc[0][t] + sc[1][t] + sc[2][t] + sc[3][t];
    part[((size_t)bh * 16 + chunk) * NCq + t] = v;
  }
}

// ---------------- K5: stage-2 attention; topk folded in (per-block) -------
__global__ __launch_bounds__(256, 2) void stage2_mfma(
    const char* __restrict__ qim, const float* __restrict__ ks,
    const float* __restrict__ vs, const float* __restrict__ part,
    char* __restrict__ at) {
  const int bh = blockIdx.y, b = bh >> 3, h = bh & 7;
  const int t = threadIdx.x, l = t & 63, wid = t >> 6;
  __shared__ __align__(16) short kimg[2][2048];
  __shared__ __align__(16) short vimg[2][2][1024];
  __shared__ float pbuf[128][66];
  __shared__ float sco[NCq];
  __shared__ int ibs[64];

  bf16x8 ah[2], al[2];
  {
    const char* qb = qim + ((size_t)(bh * 64 + blockIdx.x * 2 + (wid >> 1))) * 8192;
#pragma unroll
    for (int kd = 0; kd < 2; ++kd) {
      int off = ((wid & 1) * 2 + kd) * 1024 + l * 16;
      ah[kd] = *(const bf16x8*)(qb + off);
      al[kd] = *(const bf16x8*)(qb + 4096 + off);
    }
  }
  // redundant per-block reduce + exact stable top-64 (deterministic)
  {
    float v = 0.f;
#pragma unroll
    for (int c = 0; c < 16; ++c) v += part[((size_t)bh * 16 + c) * NCq + t];
    sco[t] = v;
  }
  __syncthreads();
  {
    float st = sco[t];
    int rank = 0;
    for (int j = 0; j < NCq; ++j) {
      float sj = sco[j];
      rank += (sj > st) || (sj == st && j < t);
    }
    if (rank < TOPKq) ibs[rank] = t;
  }
  const float* ksb = ks + ((size_t)b * Cq + h * DIMq) * NCq;
  const float* vsb = vs + ((size_t)b * Cq + h * DIMq) * NCq;
  __syncthreads();

  {  // K image (gathered by top-64 index)
    int tok = t & 63, dg = t >> 6;
    int ti = ibs[tok];
    float v[8];
#pragma unroll
    for (int j = 0; j < 8; ++j) v[j] = ksb[(size_t)(dg * 8 + j) * NCq + ti];
    uint4 hv, lv;
    split8(v, hv, lv);
    int off = ((tok >> 5) * 2 + (dg >> 1)) * 1024 + ((tok & 31) + 32 * (dg & 1)) * 16;
    *(uint4*)((char*)&kimg[0][0] + off) = hv;
    *(uint4*)((char*)&kimg[1][0] + off) = lv;
  }
  {  // V^T images
    int d = l & 31, tko = l >> 5, img = (t >> 6) >> 1, kreg = (t >> 6) & 1;
    float v[8];
#pragma unroll
    for (int j = 0; j < 8; ++j) {
      int tok = img * 32 + kreg * 16 + tko * 8 + j;
      v[j] = vsb[(size_t)d * NCq + ibs[tok]];
    }
    uint4 hv, lv;
    split8(v, hv, lv);
    int off = kreg * 1024 + (d + 32 * tko) * 16;
    *(uint4*)((char*)&vimg[0][img][0] + off) = hv;
    *(uint4*)((char*)&vimg[1][img][0] + off) = lv;
  }
  __syncthreads();

  f32x16 pacc[2];
#pragma unroll
  for (int g = 0; g < 2; ++g)
#pragma unroll
    for (int r = 0; r < 16; ++r) pacc[g][r] = 0.f;
#pragma unroll
  for (int g = 0; g < 2; ++g)
#pragma unroll
    for (int kd = 0; kd < 2; ++kd) {
      int off = (g * 2 + kd) * 1024 + l * 16;
      bf16x8 bhf = *(const bf16x8*)((const char*)&kimg[0][0] + off);
      bf16x8 blf = *(const bf16x8*)((const char*)&kimg[1][0] + off);
      pacc[g] = __builtin_amdgcn_mfma_f32_32x32x16_bf16(ah[kd], bhf, pacc[g], 0, 0, 0);
      pacc[g] = __builtin_amdgcn_mfma_f32_32x32x16_bf16(ah[kd], blf, pacc[g], 0, 0, 0);
      pacc[g] = __builtin_amdgcn_mfma_f32_32x32x16_bf16(al[kd], bhf, pacc[g], 0, 0, 0);
    }
  {
    float mx[16], sm[16];
#pragma unroll
    for (int r = 0; r < 16; ++r) mx[r] = fmaxf(pacc[0][r], pacc[1][r]);
#pragma unroll
    for (int off = 1; off < 32; off <<= 1)
#pragma unroll
      for (int r = 0; r < 16; ++r) mx[r] = fmaxf(mx[r], __shfl_xor(mx[r], off));
#pragma unroll
    for (int r = 0; r < 16; ++r) {
      float e0 = __expf((pacc[0][r] - mx[r]) * SCALEq);
      float e1 = __expf((pacc[1][r] - mx[r]) * SCALEq);
      pacc[0][r] = e0; pacc[1][r] = e1;
      sm[r] = e0 + e1;
    }
#pragma unroll
    for (int off = 1; off < 32; off <<= 1)
#pragma unroll
      for (int r = 0; r < 16; ++r) sm[r] += __shfl_xor(sm[r], off);
#pragma unroll
    for (int r = 0; r < 16; ++r) sm[r] = 1.0f / sm[r];
#pragma unroll
    for (int g = 0; g < 2; ++g)
#pragma unroll
      for (int r = 0; r < 16; ++r) {
        int qrow = wid * 32 + (r & 3) + 8 * (r >> 2) + 4 * (l >> 5);
        pbuf[qrow][g * 32 + (l & 31)] = pacc[g][r] * sm[r];
      }
  }
  __syncthreads();
  f32x16 oacc;
#pragma unroll
  for (int r = 0; r < 16; ++r) oacc[r] = 0.f;
#pragma unroll
  for (int ks4 = 0; ks4 < 4; ++ks4) {
    const float* pa = &pbuf[wid * 32 + (l & 31)][ks4 * 16 + (l >> 5) * 8];
    float v[8];
#pragma unroll
    for (int j = 0; j < 8; ++j) v[j] = pa[j];
    uint4 hv, lv;
    split8(v, hv, lv);
    bf16x8 pah = *(const bf16x8*)&hv, pal = *(const bf16x8*)&lv;
    int off = (ks4 & 1) * 1024 + l * 16;
    bf16x8 bhf = *(const bf16x8*)((const char*)&vimg[0][ks4 >> 1][0] + off);
    bf16x8 blf = *(const bf16x8*)((const char*)&vimg[1][ks4 >> 1][0] + off);
    oacc = __builtin_amdgcn_mfma_f32_32x32x16_bf16(pah, bhf, oacc, 0, 0, 0);
    oacc = __builtin_amdgcn_mfma_f32_32x32x16_bf16(pah, blf, oacc, 0, 0, 0);
    oacc = __builtin_amdgcn_mfma_f32_32x32x16_bf16(pal, bhf, oacc, 0, 0, 0);
  }
#pragma unroll
  for (int r = 0; r < 16; ++r) {
    int qrow = wid * 32 + (r & 3) + 8 * (r >> 2) + 4 * (l >> 5);
    pbuf[qrow][l & 31] = oacc[r];
  }
  __syncthreads();
#pragma unroll
  for (int ii = 0; ii < 2; ++ii) {
    int slot = t + ii * 256;
    int row = slot >> 2, dg = slot & 3;
    float v[8];
#pragma unroll
    for (int j = 0; j < 8; ++j) v[j] = pbuf[row][dg * 8 + j];
    uint4 hv, lv;
    split8(v, hv, lv);
    int nb = blockIdx.x * 2 + (row >> 6), nloc = row & 63;
    size_t base = ((size_t)((b * 64 + nb) * 8 + h)) * 8192;
    int off = ((nloc >> 5) * 2 + (dg >> 1)) * 1024 +
              ((nloc & 31) + 32 * (dg & 1)) * 16;
    *(uint4*)(at + base + off) = hv;
    *(uint4*)(at + base + 4096 + off) = lv;
  }
}

// ---------------- K6: output projection + bias ----------------------------
__global__ __launch_bounds__(256) void out_mfma(
    const char* __restrict__ at, const char* __restrict__ wt,
    const float* __restrict__ bo, float* __restrict__ y) {
  const int b = blockIdx.z, oblk = blockIdx.y, nblk = blockIdx.x;
  const int o0 = oblk * 64, n0 = nblk * 64;
  const int t = threadIdx.x, l = t & 63, wid = t >> 6;
  const int ob = wid >> 1, nbw = wid & 1;
  __shared__ __align__(16) char wimg[4][8192];  // 32KB half-window
  __shared__ float bs[64];
  if (t < 64) bs[t] = bo[o0 + t];

  f32x16 acc;
#pragma unroll
  for (int i = 0; i < 16; ++i) acc[i] = 0.f;

  // prologue: all 8 steps' at-fragments into registers (independent loads)
  bf16x8 xh[8][2], xl[8][2];
  const size_t atbase = ((size_t)((b * 64 + nblk) * 8)) * 8192;
  const int offb0 = (nbw * 2 + 0) * 1024 + l * 16;
  const int offb1 = (nbw * 2 + 1) * 1024 + l * 16;
#pragma unroll
  for (int s = 0; s < 8; ++s) {
    const char* xb = at + atbase + (size_t)s * 8192;
    xh[s][0] = *(const bf16x8*)(xb + offb0);
    xh[s][1] = *(const bf16x8*)(xb + offb1);
    xl[s][0] = *(const bf16x8*)(xb + 4096 + offb0);
    xl[s][1] = *(const bf16x8*)(xb + 4096 + offb1);
  }
  // stage W steps 0..3 (32KB, 8 uint4/thread)
  const uint4* wsrc = (const uint4*)(wt + ((size_t)((12 + oblk) * 8)) * 8192);
#pragma unroll
  for (int u = 0; u < 8; ++u)
    ((uint4*)&wimg[0][0])[t + u * 256] = wsrc[t + u * 256];
  __syncthreads();

  const int offa0 = (ob * 2 + 0) * 1024 + l * 16;
  const int offa1 = (ob * 2 + 1) * 1024 + l * 16;
#pragma unroll
  for (int s = 0; s < 4; ++s) {
    const char* wb = wimg[s];
    bf16x8 ah0 = *(const bf16x8*)(wb + offa0);
    bf16x8 al0 = *(const bf16x8*)(wb + 4096 + offa0);
    bf16x8 ah1 = *(const bf16x8*)(wb + offa1);
    bf16x8 al1 = *(const bf16x8*)(wb + 4096 + offa1);
    acc = __builtin_amdgcn_mfma_f32_32x32x16_bf16(ah0, xh[s][0], acc, 0, 0, 0);
    acc = __builtin_amdgcn_mfma_f32_32x32x16_bf16(ah0, xl[s][0], acc, 0, 0, 0);
    acc = __builtin_amdgcn_mfma_f32_32x32x16_bf16(al0, xh[s][0], acc, 0, 0, 0);
    acc = __builtin_amdgcn_mfma_f32_32x32x16_bf16(ah1, xh[s][1], acc, 0, 0, 0);
    acc = __builtin_amdgcn_mfma_f32_32x32x16_bf16(ah1, xl[s][1], acc, 0, 0, 0);
    acc = __builtin_amdgcn_mfma_f32_32x32x16_bf16(al1, xh[s][1], acc, 0, 0, 0);
  }
  __syncthreads();   // all waves done reading half 1
#pragma unroll
  for (int u = 0; u < 8; ++u)
    ((uint4*)&wimg[0][0])[t + u * 256] = wsrc[2048 + t + u * 256];
  __syncthreads();
#pragma unroll
  for (int s = 4; s < 8; ++s) {
    const char* wb = wimg[s - 4];
    bf16x8 ah0 = *(const bf16x8*)(wb + offa0);
    bf16x8 al0 = *(const bf16x8*)(wb + 4096 + offa0);
    bf16x8 ah1 = *(const bf16x8*)(wb + offa1);
    bf16x8 al1 = *(const bf16x8*)(wb + 4096 + offa1);
    acc = __builtin_amdgcn_mfma_f32_32x32x16_bf16(ah0, xh[s][0], acc, 0, 0, 0);
    acc = __builtin_amdgcn_mfma_f32_32x32x16_bf16(ah0, xl[s][0], acc, 0, 0, 0);
    acc = __builtin_amdgcn_mfma_f32_32x32x16_bf16(al0, xh[s][0], acc, 0, 0, 0);
    acc = __builtin_amdgcn_mfma_f32_32x32x16_bf16(ah1, xh[s][1], acc, 0, 0, 0);
    acc = __builtin_amdgcn_mfma_f32_32x32x16_bf16(ah1, xl[s][1], acc, 0, 0, 0);
    acc = __builtin_amdgcn_mfma_f32_32x32x16_bf16(al1, xh[s][1], acc, 0, 0, 0);
  }
#pragma unroll
  for (int r = 0; r < 16; ++r) {
    int ol = ob * 32 + (r & 3) + 8 * (r >> 2) + 4 * (l >> 5);
    y[((size_t)(b * Cq + o0 + ol)) * Nq + n0 + nbw * 32 + (l & 31)] = acc[r] + bs[ol];
  }
}

extern "C" void kernel_launch(void* const* d_in, const int* in_sizes, int n_in,
                              void* d_out, int out_size, void* d_ws, size_t ws_size,
                              hipStream_t stream) {
  const float* x   = (const float*)d_in[0];
  const float* wq  = (const float*)d_in[1];
  const float* wk  = (const float*)d_in[2];
  const float* wv  = (const float*)d_in[3];
  const float* wck = (const float*)d_in[4];
  const float* wcv = (const float*)d_in[5];
  const float* wo  = (const float*)d_in[6];
  const float* bo  = (const float*)d_in[7];
  float* out = (float*)d_out;

  char* wsb = (char*)d_ws;
  char*  qimg = wsb;                                      // 32MB
  char*  xt   = wsb + ((size_t)32 << 20);                 // 32MB
  char*  at   = xt;                                       // overlay
  char*  wt   = wsb + ((size_t)64 << 20);                 // 1MB
  char*  wt32 = wsb + ((size_t)65 << 20);                 // 0.75MB
  char*  kim  = wsb + ((size_t)66 << 20);                 // 2MB kim16 images
  float* ksc  = (float*)(wsb + ((size_t)68 << 20));       // 2MB
  float* vsc  = (float*)(wsb + ((size_t)70 << 20));       // 2MB
  float* part = (float*)(wsb + ((size_t)72 << 20));       // 1MB

  prep_wall<<<dim3(4, 8, 7), 256, 0, stream>>>(wq, wk, wv, wo, wt, wt32);
  prep_x<<<dim3(64, 8, 8), 256, 0, stream>>>(x, xt);
  qkv_fused<<<dim3(16, 8, 8), 512, 0, stream>>>(wt32, xt, wck, wcv, qimg, ksc, vsc, kim);
  stage1_mfma<<<dim3(16, BHq), 256, 0, stream>>>(qimg, kim, part);
  stage2_mfma<<<dim3(32, BHq), 256, 0, stream>>>(qimg, ksc, vsc, part, at);
  out_mfma<<<dim3(64, 4, 8), 256, 0, stream>>>(at, wt, bo, out);
}

// Round 21
// 175.303 us; speedup vs baseline: 1.1072x; 1.1072x over previous
//
#include <hip/hip_runtime.h>

#define Bq 8
#define Cq 256
#define Hq 64
#define Wq 64
#define Nq 4096        // H*W
#define HEADSq 8
#define DIMq 32
#define NCq 256        // compressed tokens 16*16
#define TOPKq 64
#define BHq 64
#define SCALEq 0.17677669529663687f   // 32^-0.5

typedef short bf16x8 __attribute__((ext_vector_type(8)));
typedef float f32x4  __attribute__((ext_vector_type(4)));
typedef float f32x16 __attribute__((ext_vector_type(16)));

// round-to-nearest-even bf16 (top 16 bits)
__device__ __forceinline__ uint32_t f2bf_hi(float f) {
  uint32_t u = __float_as_uint(f);
  return (u + 0x7FFFu + ((u >> 16) & 1u)) >> 16;
}

// split 8 floats into bf16 hi (RNE) + bf16 lo (residual, truncated), packed
__device__ __forceinline__ void split8(const float* v, uint4& hv, uint4& lv) {
  uint32_t h[8], l[8];
#pragma unroll
  for (int j = 0; j < 8; ++j) {
    uint32_t hb = f2bf_hi(v[j]);
    float rest = v[j] - __uint_as_float(hb << 16);
    h[j] = hb;
    l[j] = __float_as_uint(rest) >> 16;
  }
  hv = make_uint4(h[0] | (h[1] << 16), h[2] | (h[3] << 16),
                  h[4] | (h[5] << 16), h[6] | (h[7] << 16));
  lv = make_uint4(l[0] | (l[1] << 16), l[2] | (l[3] << 16),
                  l[4] | (l[5] << 16), l[6] | (l[7] << 16));
}

// 64-row fragment image (8KB = hi 4KB | lo 4KB), element (row,k):
//   region=(row>>5)*2+(k>>4), lane=(row&31)+32*((k&15)>>3), byte=region*1024+lane*16+(k&7)*2
// 32-row image (4KB = hi 2KB | lo 2KB): off=(k>>4)*1024+lane*16, lo at +2048.
// kim16: B-frag-linear K image for 16x16x32: unit (tt,l) at bh*32768 + tt*1024
//   + l*16 (hi; lo +16384) holding K[tok=tt*16+(l&15), k-octet l>>4].

// ---------------- P0: wo -> 64o images (for out_mfma) ---------------------
__global__ __launch_bounds__(256) void prep_w(
    const float* __restrict__ wq, const float* __restrict__ wk,
    const float* __restrict__ wv, const float* __restrict__ wo,
    char* __restrict__ wt) {
  const int oblk = blockIdx.x, s = blockIdx.y, mat = blockIdx.z;
  const float* w = mat == 0 ? wq : mat == 1 ? wk : mat == 2 ? wv : wo;
  const int t = threadIdx.x;
  const int o = t & 63, g = t >> 6;
  float v[8];
  const float* src = w + (size_t)(oblk * 64 + o) * Cq + s * 32 + g * 8;
#pragma unroll
  for (int j = 0; j < 8; ++j) v[j] = src[j];
  uint4 hv, lv;
  split8(v, hv, lv);
  size_t base = ((size_t)((mat * 4 + oblk) * 8 + s)) * 8192;
  int off = ((o >> 5) * 2 + (g >> 1)) * 1024 + ((o & 31) + 32 * (g & 1)) * 16;
  *(uint4*)(wt + base + off) = hv;
  *(uint4*)(wt + base + 4096 + off) = lv;
}

// ---------------- P1: wq/wk/wv -> 32o images ------------------------------
__global__ __launch_bounds__(128) void prep_w32(
    const float* __restrict__ wq, const float* __restrict__ wk,
    const float* __restrict__ wv, char* __restrict__ wt32) {
  const int oblk = blockIdx.x, s = blockIdx.y, mat = blockIdx.z;
  const float* w = mat == 0 ? wq : mat == 1 ? wk : wv;
  const int t = threadIdx.x;
  const int o = t & 31, g = t >> 5;
  float v[8];
  const float* src = w + (size_t)(oblk * 32 + o) * Cq + s * 32 + g * 8;
#pragma unroll
  for (int j = 0; j < 8; ++j) v[j] = src[j];
  uint4 hv, lv;
  split8(v, hv, lv);
  size_t base = ((size_t)((mat * 8 + oblk) * 8 + s)) * 4096;
  int off = (g >> 1) * 1024 + (o + 32 * (g & 1)) * 16;
  *(uint4*)(wt32 + base + off) = hv;
  *(uint4*)(wt32 + base + 2048 + off) = lv;
}

// ---------------- P2: x -> transposed/split B-frag images (32n x 32k) -----
__global__ __launch_bounds__(256) void prep_x(
    const float* __restrict__ x, char* __restrict__ xt) {
  const int n64 = blockIdx.x, s = blockIdx.y, b = blockIdx.z;
  const int t = threadIdx.x;
  __shared__ float xf[32][64];
  const float* xb = x + ((size_t)(b * Cq + s * 32)) * Nq + n64 * 64;
#pragma unroll
  for (int ii = 0; ii < 2; ++ii) {
    int e = t + ii * 256;
    int cl = e >> 4, n4 = (e & 15) * 4;
    *(float4*)&xf[cl][n4] = *(const float4*)&xb[(size_t)cl * Nq + n4];
  }
  __syncthreads();
  int n = t & 63, g = t >> 6;
  float v[8];
#pragma unroll
  for (int j = 0; j < 8; ++j) v[j] = xf[g * 8 + j][n];
  uint4 hv, lv;
  split8(v, hv, lv);
  char* dst = xt + ((size_t)((b * 8 + s) * 128 + n64 * 2 + (n >> 5))) * 4096;
  int off = (g >> 1) * 1024 + ((n & 31) + 32 * (g & 1)) * 16;
  *(uint4*)(dst + off) = hv;
  *(uint4*)(dst + 2048 + off) = lv;
}

// ---------------- K1: fused qkv projection + pool; emits kim16 ------------
// 512 threads / 8 waves; each wave owns 32o x 32n x 3mats -> acc[3] = 48
// AGPRs so 4+ waves/SIMD co-reside and hide x-load latency.
__global__ __launch_bounds__(512) void qkv_fused(
    const char* __restrict__ wt32, const char* __restrict__ xt,
    const float* __restrict__ wck, const float* __restrict__ wcv,
    char* __restrict__ qimg, float* __restrict__ ksc, float* __restrict__ vsc,
    char* __restrict__ kim) {
  const int i = blockIdx.x, oblk = blockIdx.y, b = blockIdx.z;
  const int t = threadIdx.x, l = t & 63, wid = t >> 6;   // wid 0..7
  __shared__ __align__(16) short wimg[3][2][1024];  // 12KB
  __shared__ float pp[8][2][32][8];                 // 16KB pool partials
  __shared__ float wpool[2][32][16];                // 4KB (reused as pools)

  for (int u = t; u < 1024; u += 512) {
    int m = u >> 9, c = (u >> 4) & 31, e = u & 15;
    wpool[m][c][e] = (m ? wcv : wck)[(oblk * 32 + c) * 16 + e];
  }

  f32x16 acc[3];
#pragma unroll
  for (int m = 0; m < 3; ++m)
#pragma unroll
    for (int r = 0; r < 16; ++r) acc[m][r] = 0.f;

#pragma unroll 1
  for (int s = 0; s < 8; ++s) {
    __syncthreads();
#pragma unroll
    for (int u = 0; u < 2; ++u) {   // stage W(s): 768 uint4 over 512 thr
      int e = t + u * 512;
      if (e < 768) {
        int m = e >> 8, r = e & 255;
        ((uint4*)&wimg[m][0][0])[r] =
            ((const uint4*)(wt32 + ((size_t)((m * 8 + oblk) * 8 + s)) * 4096))[r];
      }
    }
    __syncthreads();
    // wave's private x image (32n x 32k): 4 x 16B coalesced loads
    bf16x8 xh[2], xl[2];
    {
      const char* xb = xt + ((size_t)((b * 8 + s) * 128 + i * 8 + wid)) * 4096;
#pragma unroll
      for (int kh = 0; kh < 2; ++kh) {
        int off = kh * 1024 + l * 16;
        xh[kh] = *(const bf16x8*)(xb + off);
        xl[kh] = *(const bf16x8*)(xb + 2048 + off);
      }
    }
#pragma unroll
    for (int m = 0; m < 3; ++m)
#pragma unroll
      for (int kh = 0; kh < 2; ++kh) {
        int off = kh * 1024 + l * 16;
        bf16x8 ah = *(const bf16x8*)((const char*)&wimg[m][0][0] + off);
        bf16x8 al = *(const bf16x8*)((const char*)&wimg[m][1][0] + off);
        acc[m] = __builtin_amdgcn_mfma_f32_32x32x16_bf16(ah, xh[kh], acc[m], 0, 0, 0);
        acc[m] = __builtin_amdgcn_mfma_f32_32x32x16_bf16(ah, xl[kh], acc[m], 0, 0, 0);
        acc[m] = __builtin_amdgcn_mfma_f32_32x32x16_bf16(al, xh[kh], acc[m], 0, 0, 0);
      }
  }

  // k,v: in-register depthwise pool. Wave's n: spatial row = wid>>1,
  // w-coord = (wid&1)*32 + (l&31); s-sub = l&3; pooled j-local = (l&31)>>2.
#pragma unroll
  for (int m = 1; m <= 2; ++m)
#pragma unroll
    for (int r = 0; r < 16; ++r) {
      int c_l = (r & 3) + 8 * (r >> 2) + 4 * (l >> 5);
      float sv = acc[m][r] * wpool[m - 1][c_l][(wid >> 1) * 4 + (l & 3)];
      float t0 = sv + __shfl_xor(sv, 1);
      float s4 = t0 + __shfl_xor(t0, 2);
      if ((l & 3) == 0)
        pp[wid][m - 1][c_l][(l & 31) >> 2] = s4;
    }

  // q emit: image = wid>>1, rows (wid&1)*32 + (l&31), region base (wid&1)*2
  const int bh = b * 8 + oblk;
  {
    char* qb = qimg + ((size_t)(bh * 64 + i * 4 + (wid >> 1))) * 8192;
    const int hi = l >> 5;
    const int rg = (wid & 1) * 2;
    float sw[16];
#pragma unroll
    for (int r = 0; r < 16; ++r) sw[r] = __shfl_xor(acc[0][r], 32);
    float e0[8], e1[8];
#pragma unroll
    for (int j = 0; j < 4; ++j) {
      e0[j]     = hi ? sw[4 + j]      : acc[0][j];
      e0[4 + j] = hi ? acc[0][4 + j]  : sw[j];
      e1[j]     = hi ? sw[12 + j]     : acc[0][8 + j];
      e1[4 + j] = hi ? acc[0][12 + j] : sw[8 + j];
    }
    uint4 h0, l0v, h1, l1v;
    split8(e0, h0, l0v);
    split8(e1, h1, l1v);
    *(uint4*)(qb + rg * 1024 + l * 16) = h0;
    *(uint4*)(qb + 4096 + rg * 1024 + l * 16) = l0v;
    *(uint4*)(qb + (rg + 1) * 1024 + l * 16) = h1;
    *(uint4*)(qb + 4096 + (rg + 1) * 1024 + l * 16) = l1v;
  }
  __syncthreads();
  float* kpool = &wpool[0][0][0];
  float* vpool = &wpool[1][0][0];
  {
    int c = t >> 4, j = t & 15;   // 512 threads cover 32c x 16j; m looped
#pragma unroll
    for (int m = 0; m < 2; ++m) {
      int h = j >> 3, jl = j & 7;
      float v = pp[0 * 2 + h][m][c][jl] + pp[1 * 2 + h][m][c][jl] +
                pp[2 * 2 + h][m][c][jl] + pp[3 * 2 + h][m][c][jl];
      (m ? vpool : kpool)[c * 16 + j] = v;
      float* dst = m ? vsc : ksc;
      dst[((size_t)b * Cq + oblk * 32 + c) * NCq + i * 16 + j] = v;
    }
  }
  __syncthreads();
  // kim16 emit: tt == i; unit (tt,l) = K[tok=i*16+(l&15), octet l>>4]
  if (t < 64) {
    int j = l & 15, g = l >> 4;
    float v[8];
#pragma unroll
    for (int jj = 0; jj < 8; ++jj) v[jj] = kpool[(g * 8 + jj) * 16 + j];
    uint4 hv, lv;
    split8(v, hv, lv);
    char* kb = kim + (size_t)bh * 32768 + i * 1024 + l * 16;
    *(uint4*)kb = hv;
    *(uint4*)(kb + 16384) = lv;
  }
}

// ---------------- K3a: stage-1 scores, 16x16x32 MFMA ----------------------
__global__ __launch_bounds__(256) void stage1_mfma(
    const char* __restrict__ qim, const char* __restrict__ kim,
    float* __restrict__ part) {
  const int bh = blockIdx.y, chunk = blockIdx.x;
  const int t = threadIdx.x, l = t & 63, wid = t >> 6;
  __shared__ __align__(16) char kimgL[32768];   // hi 16KB | lo 16KB
  __shared__ float sc[4][256];

  {  // linear coalesced 32KB copy of this bh's kim16
    const uint4* src = (const uint4*)(kim + (size_t)bh * 32768);
#pragma unroll
    for (int ii = 0; ii < 8; ++ii)
      ((uint4*)kimgL)[t + ii * 256] = src[t + ii * 256];
  }
  float scoreacc[16];
#pragma unroll
  for (int tt = 0; tt < 16; ++tt) scoreacc[tt] = 0.f;
  // A-frag byte offset in a 64-row image: row = wid*16+(l&15), g = l>>4
  const int aoff = ((wid >> 1) * 2 + (l >> 5)) * 1024 +
                   ((wid & 1) * 16 + (l & 15) + 32 * ((l >> 4) & 1)) * 16;
  __syncthreads();

#pragma unroll 1
  for (int step = 0; step < 4; ++step) {
    const char* qb = qim + ((size_t)(bh * 64 + chunk * 4 + step)) * 8192;
    bf16x8 ah = *(const bf16x8*)(qb + aoff);
    bf16x8 al = *(const bf16x8*)(qb + 4096 + aoff);
    f32x4 acc[16];
#pragma unroll
    for (int tt = 0; tt < 16; ++tt)
#pragma unroll
      for (int r = 0; r < 4; ++r) acc[tt][r] = 0.f;
#pragma unroll
    for (int tt = 0; tt < 16; ++tt) {
      bf16x8 bhf = *(const bf16x8*)(kimgL + tt * 1024 + l * 16);
      bf16x8 blf = *(const bf16x8*)(kimgL + 16384 + tt * 1024 + l * 16);
      acc[tt] = __builtin_amdgcn_mfma_f32_16x16x32_bf16(ah, bhf, acc[tt], 0, 0, 0);
      acc[tt] = __builtin_amdgcn_mfma_f32_16x16x32_bf16(ah, blf, acc[tt], 0, 0, 0);
      acc[tt] = __builtin_amdgcn_mfma_f32_16x16x32_bf16(al, bhf, acc[tt], 0, 0, 0);
    }
    // softmax: row = (l>>4)*4+r (within wave's 16), token = tt*16+(l&15)
    float mx[4], sm[4];
#pragma unroll
    for (int r = 0; r < 4; ++r) {
      float m = acc[0][r];
#pragma unroll
      for (int tt = 1; tt < 16; ++tt) m = fmaxf(m, acc[tt][r]);
      mx[r] = m;
    }
#pragma unroll
    for (int off = 1; off < 16; off <<= 1)
#pragma unroll
      for (int r = 0; r < 4; ++r) mx[r] = fmaxf(mx[r], __shfl_xor(mx[r], off));
#pragma unroll
    for (int r = 0; r < 4; ++r) sm[r] = 0.f;
#pragma unroll
    for (int tt = 0; tt < 16; ++tt)
#pragma unroll
      for (int r = 0; r < 4; ++r) {
        float e = __expf((acc[tt][r] - mx[r]) * SCALEq);
        acc[tt][r] = e;
        sm[r] += e;
      }
#pragma unroll
    for (int off = 1; off < 16; off <<= 1)
#pragma unroll
      for (int r = 0; r < 4; ++r) sm[r] += __shfl_xor(sm[r], off);
#pragma unroll
    for (int r = 0; r < 4; ++r) sm[r] = 1.0f / sm[r];
#pragma unroll
    for (int tt = 0; tt < 16; ++tt) {
      float tp = acc[tt][0] * sm[0] + acc[tt][1] * sm[1] +
                 acc[tt][2] * sm[2] + acc[tt][3] * sm[3];
      tp += __shfl_xor(tp, 16);
      tp += __shfl_xor(tp, 32);
      scoreacc[tt] += tp;
    }
  }
  if (l < 16) {
#pragma unroll
    for (int tt = 0; tt < 16; ++tt) sc[wid][tt * 16 + l] = scoreacc[tt];
  }
  __syncthreads();
  {
    float v = sc[0][t] + sc[1][t] + sc[2][t] + sc[3][t];
    part[((size_t)bh * 16 + chunk) * NCq + t] = v;
  }
}

// ---------------- K3b+K4 fused: reduce partials + exact stable top-64 -----
__global__ __launch_bounds__(256) void reduce_topk(
    const float* __restrict__ part, int* __restrict__ idx) {
  int bh = blockIdx.x, t = threadIdx.x;
  __shared__ float s[NCq];
  float v = 0.f;
#pragma unroll
  for (int c = 0; c < 16; ++c) v += part[((size_t)bh * 16 + c) * NCq + t];
  s[t] = v;
  __syncthreads();
  float st = s[t];
  int rank = 0;
  for (int j = 0; j < NCq; ++j) {
    float sj = s[j];
    rank += (sj > st) || (sj == st && j < t);
  }
  if (rank < TOPKq) idx[bh * TOPKq + rank] = t;
}

// ---------------- K5: stage-2 attention via MFMA --------------------------
__global__ __launch_bounds__(256, 2) void stage2_mfma(
    const char* __restrict__ qim, const float* __restrict__ ks,
    const float* __restrict__ vs, const int* __restrict__ idx,
    char* __restrict__ at) {
  const int bh = blockIdx.y, b = bh >> 3, h = bh & 7;
  const int t = threadIdx.x, l = t & 63, wid = t >> 6;
  __shared__ __align__(16) short kimg[2][2048];
  __shared__ __align__(16) short vimg[2][2][1024];
  __shared__ float pbuf[128][66];
  __shared__ int ibs[64];

  bf16x8 ah[2], al[2];
  {
    const char* qb = qim + ((size_t)(bh * 64 + blockIdx.x * 2 + (wid >> 1))) * 8192;
#pragma unroll
    for (int kd = 0; kd < 2; ++kd) {
      int off = ((wid & 1) * 2 + kd) * 1024 + l * 16;
      ah[kd] = *(const bf16x8*)(qb + off);
      al[kd] = *(const bf16x8*)(qb + 4096 + off);
    }
  }
  const float* ksb = ks + ((size_t)b * Cq + h * DIMq) * NCq;
  const float* vsb = vs + ((size_t)b * Cq + h * DIMq) * NCq;
  if (t < 64) ibs[t] = idx[bh * TOPKq + t];
  __syncthreads();

  {  // K image (gathered by top-64 index)
    int tok = t & 63, dg = t >> 6;
    int ti = ibs[tok];
    float v[8];
#pragma unroll
    for (int j = 0; j < 8; ++j) v[j] = ksb[(size_t)(dg * 8 + j) * NCq + ti];
    uint4 hv, lv;
    split8(v, hv, lv);
    int off = ((tok >> 5) * 2 + (dg >> 1)) * 1024 + ((tok & 31) + 32 * (dg & 1)) * 16;
    *(uint4*)((char*)&kimg[0][0] + off) = hv;
    *(uint4*)((char*)&kimg[1][0] + off) = lv;
  }
  {  // V^T images
    int d = l & 31, tko = l >> 5, img = (t >> 6) >> 1, kreg = (t >> 6) & 1;
    float v[8];
#pragma unroll
    for (int j = 0; j < 8; ++j) {
      int tok = img * 32 + kreg * 16 + tko * 8 + j;
      v[j] = vsb[(size_t)d * NCq + ibs[tok]];
    }
    uint4 hv, lv;
    split8(v, hv, lv);
    int off = kreg * 1024 + (d + 32 * tko) * 16;
    *(uint4*)((char*)&vimg[0][img][0] + off) = hv;
    *(uint4*)((char*)&vimg[1][img][0] + off) = lv;
  }
  __syncthreads();

  f32x16 pacc[2];
#pragma unroll
  for (int g = 0; g < 2; ++g)
#pragma unroll
    for (int r = 0; r < 16; ++r) pacc[g][r] = 0.f;
#pragma unroll
  for (int g = 0; g < 2; ++g)
#pragma unroll
    for (int kd = 0; kd < 2; ++kd) {
      int off = (g * 2 + kd) * 1024 + l * 16;
      bf16x8 bhf = *(const bf16x8*)((const char*)&kimg[0][0] + off);
      bf16x8 blf = *(const bf16x8*)((const char*)&kimg[1][0] + off);
      pacc[g] = __builtin_amdgcn_mfma_f32_32x32x16_bf16(ah[kd], bhf, pacc[g], 0, 0, 0);
      pacc[g] = __builtin_amdgcn_mfma_f32_32x32x16_bf16(ah[kd], blf, pacc[g], 0, 0, 0);
      pacc[g] = __builtin_amdgcn_mfma_f32_32x32x16_bf16(al[kd], bhf, pacc[g], 0, 0, 0);
    }
  {
    float mx[16], sm[16];
#pragma unroll
    for (int r = 0; r < 16; ++r) mx[r] = fmaxf(pacc[0][r], pacc[1][r]);
#pragma unroll
    for (int off = 1; off < 32; off <<= 1)
#pragma unroll
      for (int r = 0; r < 16; ++r) mx[r] = fmaxf(mx[r], __shfl_xor(mx[r], off));
#pragma unroll
    for (int r = 0; r < 16; ++r) {
      float e0 = __expf((pacc[0][r] - mx[r]) * SCALEq);
      float e1 = __expf((pacc[1][r] - mx[r]) * SCALEq);
      pacc[0][r] = e0; pacc[1][r] = e1;
      sm[r] = e0 + e1;
    }
#pragma unroll
    for (int off = 1; off < 32; off <<= 1)
#pragma unroll
      for (int r = 0; r < 16; ++r) sm[r] += __shfl_xor(sm[r], off);
#pragma unroll
    for (int r = 0; r < 16; ++r) sm[r] = 1.0f / sm[r];
#pragma unroll
    for (int g = 0; g < 2; ++g)
#pragma unroll
      for (int r = 0; r < 16; ++r) {
        int qrow = wid * 32 + (r & 3) + 8 * (r >> 2) + 4 * (l >> 5);
        pbuf[qrow][g * 32 + (l & 31)] = pacc[g][r] * sm[r];
      }
  }
  __syncthreads();
  f32x16 oacc;
#pragma unroll
  for (int r = 0; r < 16; ++r) oacc[r] = 0.f;
#pragma unroll
  for (int ks4 = 0; ks4 < 4; ++ks4) {
    const float* pa = &pbuf[wid * 32 + (l & 31)][ks4 * 16 + (l >> 5) * 8];
    float v[8];
#pragma unroll
    for (int j = 0; j < 8; ++j) v[j] = pa[j];
    uint4 hv, lv;
    split8(v, hv, lv);
    bf16x8 pah = *(const bf16x8*)&hv, pal = *(const bf16x8*)&lv;
    int off = (ks4 & 1) * 1024 + l * 16;
    bf16x8 bhf = *(const bf16x8*)((const char*)&vimg[0][ks4 >> 1][0] + off);
    bf16x8 blf = *(const bf16x8*)((const char*)&vimg[1][ks4 >> 1][0] + off);
    oacc = __builtin_amdgcn_mfma_f32_32x32x16_bf16(pah, bhf, oacc, 0, 0, 0);
    oacc = __builtin_amdgcn_mfma_f32_32x32x16_bf16(pah, blf, oacc, 0, 0, 0);
    oacc = __builtin_amdgcn_mfma_f32_32x32x16_bf16(pal, bhf, oacc, 0, 0, 0);
  }
#pragma unroll
  for (int r = 0; r < 16; ++r) {
    int qrow = wid * 32 + (r & 3) + 8 * (r >> 2) + 4 * (l >> 5);
    pbuf[qrow][l & 31] = oacc[r];
  }
  __syncthreads();
#pragma unroll
  for (int ii = 0; ii < 2; ++ii) {
    int slot = t + ii * 256;
    int row = slot >> 2, dg = slot & 3;
    float v[8];
#pragma unroll
    for (int j = 0; j < 8; ++j) v[j] = pbuf[row][dg * 8 + j];
    uint4 hv, lv;
    split8(v, hv, lv);
    int nb = blockIdx.x * 2 + (row >> 6), nloc = row & 63;
    size_t base = ((size_t)((b * 64 + nb) * 8 + h)) * 8192;
    int off = ((nloc >> 5) * 2 + (dg >> 1)) * 1024 +
              ((nloc & 31) + 32 * (dg & 1)) * 16;
    *(uint4*)(at + base + off) = hv;
    *(uint4*)(at + base + 4096 + off) = lv;
  }
}

// ---------------- K6: output projection + bias ----------------------------
__global__ __launch_bounds__(256) void out_mfma(
    const char* __restrict__ at, const char* __restrict__ wt,
    const float* __restrict__ bo, float* __restrict__ y) {
  const int b = blockIdx.z, oblk = blockIdx.y, nblk = blockIdx.x;
  const int o0 = oblk * 64, n0 = nblk * 64;
  const int t = threadIdx.x, l = t & 63, wid = t >> 6;
  const int ob = wid >> 1, nbw = wid & 1;
  __shared__ __align__(16) char wimg[4][8192];  // 32KB half-window
  __shared__ float bs[64];
  if (t < 64) bs[t] = bo[o0 + t];

  f32x16 acc;
#pragma unroll
  for (int i = 0; i < 16; ++i) acc[i] = 0.f;

  // prologue: all 8 steps' at-fragments into registers (independent loads)
  bf16x8 xh[8][2], xl[8][2];
  const size_t atbase = ((size_t)((b * 64 + nblk) * 8)) * 8192;
  const int offb0 = (nbw * 2 + 0) * 1024 + l * 16;
  const int offb1 = (nbw * 2 + 1) * 1024 + l * 16;
#pragma unroll
  for (int s = 0; s < 8; ++s) {
    const char* xb = at + atbase + (size_t)s * 8192;
    xh[s][0] = *(const bf16x8*)(xb + offb0);
    xh[s][1] = *(const bf16x8*)(xb + offb1);
    xl[s][0] = *(const bf16x8*)(xb + 4096 + offb0);
    xl[s][1] = *(const bf16x8*)(xb + 4096 + offb1);
  }
  // stage W steps 0..3 (32KB, 8 uint4/thread)
  const uint4* wsrc = (const uint4*)(wt + ((size_t)((12 + oblk) * 8)) * 8192);
#pragma unroll
  for (int u = 0; u < 8; ++u)
    ((uint4*)&wimg[0][0])[t + u * 256] = wsrc[t + u * 256];
  __syncthreads();

  const int offa0 = (ob * 2 + 0) * 1024 + l * 16;
  const int offa1 = (ob * 2 + 1) * 1024 + l * 16;
#pragma unroll
  for (int s = 0; s < 4; ++s) {
    const char* wb = wimg[s];
    bf16x8 ah0 = *(const bf16x8*)(wb + offa0);
    bf16x8 al0 = *(const bf16x8*)(wb + 4096 + offa0);
    bf16x8 ah1 = *(const bf16x8*)(wb + offa1);
    bf16x8 al1 = *(const bf16x8*)(wb + 4096 + offa1);
    acc = __builtin_amdgcn_mfma_f32_32x32x16_bf16(ah0, xh[s][0], acc, 0, 0, 0);
    acc = __builtin_amdgcn_mfma_f32_32x32x16_bf16(ah0, xl[s][0], acc, 0, 0, 0);
    acc = __builtin_amdgcn_mfma_f32_32x32x16_bf16(al0, xh[s][0], acc, 0, 0, 0);
    acc = __builtin_amdgcn_mfma_f32_32x32x16_bf16(ah1, xh[s][1], acc, 0, 0, 0);
    acc = __builtin_amdgcn_mfma_f32_32x32x16_bf16(ah1, xl[s][1], acc, 0, 0, 0);
    acc = __builtin_amdgcn_mfma_f32_32x32x16_bf16(al1, xh[s][1], acc, 0, 0, 0);
  }
  __syncthreads();   // all waves done reading half 1
#pragma unroll
  for (int u = 0; u < 8; ++u)
    ((uint4*)&wimg[0][0])[t + u * 256] = wsrc[2048 + t + u * 256];
  __syncthreads();
#pragma unroll
  for (int s = 4; s < 8; ++s) {
    const char* wb = wimg[s - 4];
    bf16x8 ah0 = *(const bf16x8*)(wb + offa0);
    bf16x8 al0 = *(const bf16x8*)(wb + 4096 + offa0);
    bf16x8 ah1 = *(const bf16x8*)(wb + offa1);
    bf16x8 al1 = *(const bf16x8*)(wb + 4096 + offa1);
    acc = __builtin_amdgcn_mfma_f32_32x32x16_bf16(ah0, xh[s][0], acc, 0, 0, 0);
    acc = __builtin_amdgcn_mfma_f32_32x32x16_bf16(ah0, xl[s][0], acc, 0, 0, 0);
    acc = __builtin_amdgcn_mfma_f32_32x32x16_bf16(al0, xh[s][0], acc, 0, 0, 0);
    acc = __builtin_amdgcn_mfma_f32_32x32x16_bf16(ah1, xh[s][1], acc, 0, 0, 0);
    acc = __builtin_amdgcn_mfma_f32_32x32x16_bf16(ah1, xl[s][1], acc, 0, 0, 0);
    acc = __builtin_amdgcn_mfma_f32_32x32x16_bf16(al1, xh[s][1], acc, 0, 0, 0);
  }
#pragma unroll
  for (int r = 0; r < 16; ++r) {
    int ol = ob * 32 + (r & 3) + 8 * (r >> 2) + 4 * (l >> 5);
    y[((size_t)(b * Cq + o0 + ol)) * Nq + n0 + nbw * 32 + (l & 31)] = acc[r] + bs[ol];
  }
}

extern "C" void kernel_launch(void* const* d_in, const int* in_sizes, int n_in,
                              void* d_out, int out_size, void* d_ws, size_t ws_size,
                              hipStream_t stream) {
  const float* x   = (const float*)d_in[0];
  const float* wq  = (const float*)d_in[1];
  const float* wk  = (const float*)d_in[2];
  const float* wv  = (const float*)d_in[3];
  const float* wck = (const float*)d_in[4];
  const float* wcv = (const float*)d_in[5];
  const float* wo  = (const float*)d_in[6];
  const float* bo  = (const float*)d_in[7];
  float* out = (float*)d_out;

  char* wsb = (char*)d_ws;
  char*  qimg = wsb;                                      // 32MB
  char*  xt   = wsb + ((size_t)32 << 20);                 // 32MB
  char*  at   = xt;                                       // overlay
  char*  wt   = wsb + ((size_t)64 << 20);                 // 1MB
  char*  wt32 = wsb + ((size_t)65 << 20);                 // 0.75MB
  char*  kim  = wsb + ((size_t)66 << 20);                 // 2MB kim16 images
  float* ksc  = (float*)(wsb + ((size_t)68 << 20));       // 2MB
  float* vsc  = (float*)(wsb + ((size_t)70 << 20));       // 2MB
  float* part = (float*)(wsb + ((size_t)72 << 20));       // 1MB
  int*   idx  = (int*)(wsb + ((size_t)73 << 20));

  prep_w<<<dim3(4, 8, 4), 256, 0, stream>>>(wq, wk, wv, wo, wt);
  prep_w32<<<dim3(8, 8, 3), 128, 0, stream>>>(wq, wk, wv, wt32);
  prep_x<<<dim3(64, 8, 8), 256, 0, stream>>>(x, xt);
  qkv_fused<<<dim3(16, 8, 8), 512, 0, stream>>>(wt32, xt, wck, wcv, qimg, ksc, vsc, kim);
  stage1_mfma<<<dim3(16, BHq), 256, 0, stream>>>(qimg, kim, part);
  reduce_topk<<<dim3(BHq), 256, 0, stream>>>(part, idx);
  stage2_mfma<<<dim3(32, BHq), 256, 0, stream>>>(qimg, ksc, vsc, idx, at);
  out_mfma<<<dim3(64, 4, 8), 256, 0, stream>>>(at, wt, bo, out);
}